// Round 11
// baseline (3332.163 us; speedup 1.0000x reference)
//
#include <hip/hip_runtime.h>
#include <hip/hip_bf16.h>
#include <stdint.h>

typedef __attribute__((ext_vector_type(8))) short bf16x8;
typedef __attribute__((ext_vector_type(4))) float f32x4;
typedef __attribute__((ext_vector_type(4))) unsigned int u32x4;
typedef unsigned long long ull_t;

#define S_LEN 512
#define B_DIM 64
#define E_DIM 512
#define H_DIM 768
#define G4    3072      // 4H (one direction's gate width)
#define H2    1536      // 2H (combined hs row)
#define M_ROWS 32768    // S*B
#define CHUNK 128       // seq steps per X-chunk
#define CM    8192      // CHUNK*B rows per chunk
#define SLW   24        // cols per slice
#define WPS   8         // published words per slice per row
#define WPR   256       // packed words per h row (256*3 = 768 cols)
#define RWRD  4096      // words per ring per parity (16 rows * 256)
#define PSTR  16384     // words per parity (4 rings)
#define KRES  640       // K columns resident in LDS (fwd scan)
#define KREG  4         // K-tail tiles in registers (fwd scan)
#define WROW  648       // padded LDS weight row, fwd (shorts)
#define NTILES 1536     // X-GEMM tiles per chunk (64 m x 24 n)

__device__ __forceinline__ float sigmf_(float x) { return 1.0f / (1.0f + __expf(-x)); }
__device__ __forceinline__ float tanhf2(float x) {
  x = fminf(fmaxf(x, -20.0f), 20.0f);
  float e = __expf(2.0f * x);
  return (e - 1.0f) / (e + 1.0f);
}
__device__ __forceinline__ float bfu(unsigned short u) { return __uint_as_float((unsigned)u << 16); }
__device__ __forceinline__ unsigned short packbf(float a) {
  __hip_bfloat16 t = __float2bfloat16(a);
  unsigned short b;
  __builtin_memcpy(&b, &t, 2);
  return b;
}

// ---------------- embedding gather + cast to bf16 ----------------
__global__ __launch_bounds__(256) void k_gather(const int* __restrict__ tokens,
                                                const float* __restrict__ emb,
                                                __hip_bfloat16* __restrict__ out) {
  const int t = blockIdx.x * 256 + threadIdx.x;
  const int e0 = t * 8;
  const int row = e0 >> 9;
  const int k = e0 & 511;
  const int tok = tokens[row];
  const float4* p = (const float4*)(emb + (size_t)tok * E_DIM + k);
  const float4 v0 = p[0], v1 = p[1];
  __align__(16) __hip_bfloat16 tmp[8];
  tmp[0] = __float2bfloat16(v0.x); tmp[1] = __float2bfloat16(v0.y);
  tmp[2] = __float2bfloat16(v0.z); tmp[3] = __float2bfloat16(v0.w);
  tmp[4] = __float2bfloat16(v1.x); tmp[5] = __float2bfloat16(v1.y);
  tmp[6] = __float2bfloat16(v1.z); tmp[7] = __float2bfloat16(v1.w);
  *(bf16x8*)(out + (size_t)t * 8) = *(const bf16x8*)tmp;
}

// ---------------- fp32 -> bf16 transpose (LDS tiled): dst[c*Rs+r]=src[r*Cs+c] ----------------
__global__ __launch_bounds__(256) void k_transpose_cast(const float* __restrict__ src,
                                                        __hip_bfloat16* __restrict__ dst,
                                                        int Rs, int Cs) {
  __shared__ float tile[32][33];
  const int tx = threadIdx.x & 31, ty = threadIdx.x >> 5;
  const int c0 = blockIdx.x * 32, r0 = blockIdx.y * 32;
  #pragma unroll
  for (int i = ty; i < 32; i += 8)
    tile[i][tx] = src[(size_t)(r0 + i) * Cs + c0 + tx];
  __syncthreads();
  #pragma unroll
  for (int i = ty; i < 32; i += 8)
    dst[(size_t)(c0 + i) * Rs + r0 + tx] = __float2bfloat16(tile[tx][i]);
}

// ---------------- combined bias for one direction: bi + bh ----------------
__global__ __launch_bounds__(256) void k_bias(const float* __restrict__ bi,
                                              const float* __restrict__ bh,
                                              float* __restrict__ bias) {
  const int n = blockIdx.x * 256 + threadIdx.x;
  bias[n] = bi[n] + bh[n];
}

// ---------------- X-GEMM tile, pre-gathered bf16 A (fast path) --------
__device__ __forceinline__ void gemm_tile_e(char* pool, int tile,
                                            const __hip_bfloat16* __restrict__ A,
                                            const __hip_bfloat16* __restrict__ BT,
                                            const float* __restrict__ bias,
                                            __hip_bfloat16* __restrict__ C) {
  auto As = (__hip_bfloat16 (*)[40])pool;
  auto Bs = (__hip_bfloat16 (*)[40])(pool + 10240);
  const int tid = threadIdx.x;
  const int wave = tid >> 6, lane = tid & 63;
  const int q = lane >> 4, lr = lane & 15;
  const int wm = (wave >> 1) * 64, wn = (wave & 1) * 64;
  const int nb = tile % 24, mb = tile / 24;
  const int m0 = mb * 128, n0 = nb * 128;
  const int srow = tid >> 2, skseg = (tid & 3) * 8;

  f32x4 acc[4][4];
  #pragma unroll
  for (int i = 0; i < 4; ++i)
    #pragma unroll
    for (int j = 0; j < 4; ++j) { f32x4 z = {0.f, 0.f, 0.f, 0.f}; acc[i][j] = z; }

  for (int kt = 0; kt < 16; ++kt) {
    __syncthreads();
    const int kbase = kt * 32 + skseg;
    *(bf16x8*)&As[srow][skseg]      = *(const bf16x8*)(A + (size_t)(m0 + srow) * E_DIM + kbase);
    *(bf16x8*)&As[srow + 64][skseg] = *(const bf16x8*)(A + (size_t)(m0 + srow + 64) * E_DIM + kbase);
    *(bf16x8*)&Bs[srow][skseg]      = *(const bf16x8*)(BT + (size_t)(n0 + srow) * E_DIM + kbase);
    *(bf16x8*)&Bs[srow + 64][skseg] = *(const bf16x8*)(BT + (size_t)(n0 + srow + 64) * E_DIM + kbase);
    __syncthreads();
    bf16x8 af[4], bfr[4];
    #pragma unroll
    for (int mt = 0; mt < 4; ++mt) af[mt] = *(const bf16x8*)&As[wm + mt * 16 + lr][q * 8];
    #pragma unroll
    for (int nt = 0; nt < 4; ++nt) bfr[nt] = *(const bf16x8*)&Bs[wn + nt * 16 + lr][q * 8];
    #pragma unroll
    for (int mt = 0; mt < 4; ++mt)
      #pragma unroll
      for (int nt = 0; nt < 4; ++nt)
        acc[mt][nt] = __builtin_amdgcn_mfma_f32_16x16x32_bf16(af[mt], bfr[nt], acc[mt][nt], 0, 0, 0);
  }
  #pragma unroll
  for (int mt = 0; mt < 4; ++mt) {
    #pragma unroll
    for (int nt = 0; nt < 4; ++nt) {
      const int col = n0 + wn + nt * 16 + lr;
      const float bv = bias[col];
      #pragma unroll
      for (int i = 0; i < 4; ++i) {
        const int row = m0 + wm + mt * 16 + q * 4 + i;
        C[(size_t)row * G4 + col] = __float2bfloat16(acc[mt][nt][i] + bv);
      }
    }
  }
}

// ---------------- X-GEMM tile with fused embedding gather (fallback tiers) ----------------
__device__ __forceinline__ void gemm_tile_g(char* pool, int tile,
                                            const int* __restrict__ tokens_c,
                                            const float* __restrict__ emb,
                                            const __hip_bfloat16* __restrict__ BT,
                                            const float* __restrict__ bias,
                                            __hip_bfloat16* __restrict__ C) {
  auto As = (__hip_bfloat16 (*)[40])pool;
  auto Bs = (__hip_bfloat16 (*)[40])(pool + 10240);
  const int tid = threadIdx.x;
  const int wave = tid >> 6, lane = tid & 63;
  const int q = lane >> 4, lr = lane & 15;
  const int wm = (wave >> 1) * 64, wn = (wave & 1) * 64;
  const int nb = tile % 24, mb = tile / 24;
  const int m0 = mb * 128, n0 = nb * 128;
  const int srow = tid >> 2, skseg = (tid & 3) * 8;
  const int tok0 = tokens_c[m0 + srow];
  const int tok1 = tokens_c[m0 + srow + 64];

  f32x4 acc[4][4];
  #pragma unroll
  for (int i = 0; i < 4; ++i)
    #pragma unroll
    for (int j = 0; j < 4; ++j) { f32x4 z = {0.f, 0.f, 0.f, 0.f}; acc[i][j] = z; }

  for (int kt = 0; kt < 16; ++kt) {
    __syncthreads();
    const int kbase = kt * 32 + skseg;
    {
      const float* ap = emb + (size_t)tok0 * E_DIM + kbase;
      const float4 v0 = *(const float4*)ap, v1 = *(const float4*)(ap + 4);
      __align__(16) __hip_bfloat16 t8[8];
      t8[0] = __float2bfloat16(v0.x); t8[1] = __float2bfloat16(v0.y);
      t8[2] = __float2bfloat16(v0.z); t8[3] = __float2bfloat16(v0.w);
      t8[4] = __float2bfloat16(v1.x); t8[5] = __float2bfloat16(v1.y);
      t8[6] = __float2bfloat16(v1.z); t8[7] = __float2bfloat16(v1.w);
      *(bf16x8*)&As[srow][skseg] = *(const bf16x8*)t8;
    }
    {
      const float* ap = emb + (size_t)tok1 * E_DIM + kbase;
      const float4 v0 = *(const float4*)ap, v1 = *(const float4*)(ap + 4);
      __align__(16) __hip_bfloat16 t8[8];
      t8[0] = __float2bfloat16(v0.x); t8[1] = __float2bfloat16(v0.y);
      t8[2] = __float2bfloat16(v0.z); t8[3] = __float2bfloat16(v0.w);
      t8[4] = __float2bfloat16(v1.x); t8[5] = __float2bfloat16(v1.y);
      t8[6] = __float2bfloat16(v1.z); t8[7] = __float2bfloat16(v1.w);
      *(bf16x8*)&As[srow + 64][skseg] = *(const bf16x8*)t8;
    }
    *(bf16x8*)&Bs[srow][skseg]      = *(const bf16x8*)(BT + (size_t)(n0 + srow) * E_DIM + kbase);
    *(bf16x8*)&Bs[srow + 64][skseg] = *(const bf16x8*)(BT + (size_t)(n0 + srow + 64) * E_DIM + kbase);
    __syncthreads();
    bf16x8 af[4], bfr[4];
    #pragma unroll
    for (int mt = 0; mt < 4; ++mt) af[mt] = *(const bf16x8*)&As[wm + mt * 16 + lr][q * 8];
    #pragma unroll
    for (int nt = 0; nt < 4; ++nt) bfr[nt] = *(const bf16x8*)&Bs[wn + nt * 16 + lr][q * 8];
    #pragma unroll
    for (int mt = 0; mt < 4; ++mt)
      #pragma unroll
      for (int nt = 0; nt < 4; ++nt)
        acc[mt][nt] = __builtin_amdgcn_mfma_f32_16x16x32_bf16(af[mt], bfr[nt], acc[mt][nt], 0, 0, 0);
  }
  #pragma unroll
  for (int mt = 0; mt < 4; ++mt) {
    #pragma unroll
    for (int nt = 0; nt < 4; ++nt) {
      const int col = n0 + wn + nt * 16 + lr;
      const float bv = bias[col];
      #pragma unroll
      for (int i = 0; i < 4; ++i) {
        const int row = m0 + wm + mt * 16 + q * 4 + i;
        C[(size_t)row * G4 + col] = __float2bfloat16(acc[mt][nt][i] + bv);
      }
    }
  }
}

// ---------------- standalone X-GEMMs ----------------
__global__ __launch_bounds__(256) void k_gemm_e(const __hip_bfloat16* __restrict__ A,
                                                const __hip_bfloat16* __restrict__ BT,
                                                const float* __restrict__ bias,
                                                __hip_bfloat16* __restrict__ C) {
  __shared__ __align__(16) char pool[20480];
  gemm_tile_e(pool, blockIdx.x, A, BT, bias, C);
}
__global__ __launch_bounds__(256) void k_gemm_g(const int* __restrict__ tokens_c,
                                                const float* __restrict__ emb,
                                                const __hip_bfloat16* __restrict__ BT,
                                                const float* __restrict__ bias,
                                                __hip_bfloat16* __restrict__ C) {
  __shared__ __align__(16) char pool[20480];
  gemm_tile_g(pool, blockIdx.x, tokens_c, emb, BT, bias, C);
}

// ---------------- output block of 8 rows ----------------
__device__ __forceinline__ void out_block8(char* pool, int ob,
                                           const __hip_bfloat16* __restrict__ Hs,
                                           const float* __restrict__ Wout,
                                           const float* __restrict__ bout,
                                           const int* __restrict__ tokens,
                                           float* __restrict__ out) {
  auto rowbuf = (float (*)[1536])pool;
  const int r0 = ob * 8;
  const int tid = threadIdx.x;
  for (int idx = tid; idx < 8 * 1536; idx += 256) {
    const int rr = idx / 1536, k = idx % 1536;
    rowbuf[rr][k] = __bfloat162float(Hs[(size_t)(r0 + rr) * H2 + k]);
  }
  __syncthreads();
  const int l = tid & 31, rr = tid >> 5;
  float acc = bout[l];
  #pragma unroll 8
  for (int k = 0; k < 1536; ++k) acc += rowbuf[rr][k] * Wout[k * 32 + l];
  const int row = r0 + rr;
  if (l == 0 && tokens[row] == 1) acc += 10000.0f;
  out[(size_t)row * 32 + l] = acc;
  __syncthreads();   // rowbuf reused by next iteration
}

__global__ __launch_bounds__(256) void k_out(const __hip_bfloat16* __restrict__ Hs,
                                             const float* __restrict__ Wout,
                                             const float* __restrict__ bout,
                                             const int* __restrict__ tokens,
                                             float* __restrict__ out) {
  __shared__ __align__(16) char pool[49152];
  out_block8(pool, blockIdx.x, Hs, Wout, bout, tokens, out);
}

// ---------------- forward scan (+ co-scheduled X-GEMM workers) ----------------
// Blocks 0..127: verified tag-in-data systolic scan. Blocks 128+: persistent GEMM
// workers producing one X (next fwd chunk's, or for fwd3: backward chunk 3's).
__global__ __launch_bounds__(256, 1) void k_fwd_fused(const __hip_bfloat16* __restrict__ X,
                                                      const __hip_bfloat16* __restrict__ WhTf,
                                                      ull_t* __restrict__ hbuf,
                                                      __hip_bfloat16* __restrict__ Hs,
                                                      float* __restrict__ cstate,
                                                      float* __restrict__ hT,
                                                      int chunk,
                                                      const __hip_bfloat16* __restrict__ EmbA,
                                                      const int* __restrict__ tokens_nx,
                                                      const float* __restrict__ emb,
                                                      const __hip_bfloat16* __restrict__ WiT_nx,
                                                      const float* __restrict__ Bias_nx,
                                                      __hip_bfloat16* __restrict__ Xw) {
  __shared__ __align__(16) char pool[155904];
  const int bx = blockIdx.x;

  if (bx >= 128) {                       // ---- GEMM worker role ----
    const int nw = gridDim.x - 128;
    if (EmbA) {
      for (int t = bx - 128; t < NTILES; t += nw)
        gemm_tile_e(pool, t, EmbA, WiT_nx, Bias_nx, Xw);
    } else {
      for (int t = bx - 128; t < NTILES; t += nw)
        gemm_tile_g(pool, t, tokens_nx, emb, WiT_nx, Bias_nx, Xw);
    }
    return;
  }

  // ---- scan role: identical to the verified R4 kernel ----
  unsigned short* wlds = (unsigned short*)pool;                       // 124,416 B
  auto h_stage = (unsigned short (*)[776])(pool + 124416);            //  24,832 B
  auto g_lds   = (float (*)[16][26])(pool + 149248);                  //   6,656 B

  const int group = bx >> 5;
  const int slice = bx & 31;
  const int r0 = group * 16;
  const int j0 = slice * SLW;
  const int tid = threadIdx.x;
  const int w = tid >> 6;
  const int lane = tid & 63;
  const int q = lane >> 4, lr = lane & 15;
  const int base = chunk * CHUNK;

  const int prow = tid >> 4;
  const int pw   = tid & 15;

  const int row  = tid >> 3;
  const int wloc = tid & 7;
  const int col0 = 3 * wloc;

  for (int c = tid; c < 96 * (KRES / 8); c += 256) {
    const int r = c / (KRES / 8), k8 = c % (KRES / 8);
    const int gate = r / SLW, n = r % SLW;
    const float4 v = *(const float4*)(WhTf + (size_t)(gate * H_DIM + j0 + n) * H_DIM + k8 * 8);
    *(float4*)(wlds + (size_t)r * WROW + k8 * 8) = v;
  }

  const int wn0 = lr;
  const int wn1 = 16 + (lr & 7);
  bf16x8 wr0[KREG], wr1[KREG];
  #pragma unroll
  for (int kk = 0; kk < KREG; ++kk) {
    const int ko = KRES + kk * 32 + q * 8;
    wr0[kk] = *(const bf16x8*)(WhTf + (size_t)(w * H_DIM + j0 + wn0) * H_DIM + ko);
    wr1[kk] = *(const bf16x8*)(WhTf + (size_t)(w * H_DIM + j0 + wn1) * H_DIM + ko);
  }

  float cr[3] = {0.f, 0.f, 0.f};
  if (tid < 128) {
    const float* cs = cstate + (size_t)(r0 + row) * H_DIM + j0 + col0;
    cr[0] = cs[0]; cr[1] = cs[1]; cr[2] = cs[2];
  }

  const unsigned skipbit = ((pw >> 2) == (slice & 3)) ? (1u << (slice >> 2)) : 0u;

  __syncthreads();

  for (int s = 0; s < CHUNK; ++s) {
    const int gs = base + s;

    unsigned short xs[4][3];
    if (tid < 128) {
      const unsigned short* xp = (const unsigned short*)(X + ((size_t)s * B_DIM + r0 + row) * G4 + j0 + col0);
      #pragma unroll
      for (int g = 0; g < 4; ++g)
        #pragma unroll
        for (int j = 0; j < 3; ++j) xs[g][j] = xp[g * H_DIM + j];
    }

    const ull_t* hc = hbuf + ((size_t)(gs & 1)) * PSTR + (size_t)group * RWRD
                    + (size_t)prow * WPR + 2 * pw;
    u32x4 d0 = {0,0,0,0}, d1 = {0,0,0,0}, d2 = {0,0,0,0}, d3 = {0,0,0,0};
    u32x4 d4 = {0,0,0,0}, d5 = {0,0,0,0}, d6 = {0,0,0,0}, d7 = {0,0,0,0};
    const unsigned pollmask = (s == 0) ? 0xFFu : (0xFFu ^ skipbit);
    {
      const unsigned e16 = (unsigned)(unsigned short)gs;
      unsigned need = pollmask;
      long guard = 0;
      for (;;) {
#define POLL_LD(i, dv) \
        if (need & (1u << (i))) \
          asm volatile("global_load_dwordx4 %0, %1, off sc0 sc1" \
                       : "=v"(dv) : "v"(hc + 32 * (i)) : "memory");
        POLL_LD(0, d0) POLL_LD(1, d1) POLL_LD(2, d2) POLL_LD(3, d3)
        POLL_LD(4, d4) POLL_LD(5, d5) POLL_LD(6, d6) POLL_LD(7, d7)
#undef POLL_LD
        asm volatile("s_waitcnt vmcnt(0)"
                     : "+v"(d0), "+v"(d1), "+v"(d2), "+v"(d3),
                       "+v"(d4), "+v"(d5), "+v"(d6), "+v"(d7)
                     :: "memory");
        unsigned nn = 0;
#define POLL_CK(i, dv) \
        if ((need & (1u << (i))) && \
            ((((dv).x & 0xFFFFu) != e16) || (((dv).z & 0xFFFFu) != e16))) nn |= 1u << (i);
        POLL_CK(0, d0) POLL_CK(1, d1) POLL_CK(2, d2) POLL_CK(3, d3)
        POLL_CK(4, d4) POLL_CK(5, d5) POLL_CK(6, d6) POLL_CK(7, d7)
#undef POLL_CK
        need = nn;
        if (!need) break;
        if (++guard > (1L << 20)) break;
        __builtin_amdgcn_s_sleep(1);
      }
    }
    {
#define STAGE_PAIR(i, dv) \
      if (pollmask & (1u << (i))) { \
        unsigned* hp = (unsigned*)&h_stage[prow][6 * pw + 96 * (i)]; \
        hp[0] = ((dv).x >> 16) | ((dv).y << 16); \
        hp[1] = ((dv).y >> 16) | ((dv).z & 0xFFFF0000u); \
        hp[2] = (dv).w; \
      }
      STAGE_PAIR(0, d0) STAGE_PAIR(1, d1) STAGE_PAIR(2, d2) STAGE_PAIR(3, d3)
      STAGE_PAIR(4, d4) STAGE_PAIR(5, d5) STAGE_PAIR(6, d6) STAGE_PAIR(7, d7)
#undef STAGE_PAIR
    }
    __syncthreads();   // B1: h staged

    f32x4 acc0 = {0.f, 0.f, 0.f, 0.f};
    f32x4 acc1 = {0.f, 0.f, 0.f, 0.f};
    {
      const unsigned short* wb = wlds + (size_t)w * SLW * WROW;
      #pragma unroll
      for (int kt = 0; kt < KRES / 32; ++kt) {
        const int ko = kt * 32 + q * 8;
        const bf16x8 a  = *(const bf16x8*)&h_stage[lr][ko];
        const bf16x8 b0 = *(const bf16x8*)(wb + (size_t)wn0 * WROW + ko);
        const bf16x8 b1 = *(const bf16x8*)(wb + (size_t)wn1 * WROW + ko);
        acc0 = __builtin_amdgcn_mfma_f32_16x16x32_bf16(a, b0, acc0, 0, 0, 0);
        acc1 = __builtin_amdgcn_mfma_f32_16x16x32_bf16(a, b1, acc1, 0, 0, 0);
      }
      #pragma unroll
      for (int kk = 0; kk < KREG; ++kk) {
        const bf16x8 a = *(const bf16x8*)&h_stage[lr][KRES + kk * 32 + q * 8];
        acc0 = __builtin_amdgcn_mfma_f32_16x16x32_bf16(a, wr0[kk], acc0, 0, 0, 0);
        acc1 = __builtin_amdgcn_mfma_f32_16x16x32_bf16(a, wr1[kk], acc1, 0, 0, 0);
      }
    }
    #pragma unroll
    for (int i = 0; i < 4; ++i) g_lds[w][q * 4 + i][lr] = acc0[i];
    if (lr < 8) {
      #pragma unroll
      for (int i = 0; i < 4; ++i) g_lds[w][q * 4 + i][16 + lr] = acc1[i];
    }
    __syncthreads();   // B2: gates ready

    if (tid < 128) {
      float h[3];
      #pragma unroll
      for (int j = 0; j < 3; ++j) {
        const float rv = g_lds[0][row][col0 + j] + bfu(xs[0][j]);
        const float fv = g_lds[1][row][col0 + j] + bfu(xs[1][j]);
        const float gv = g_lds[2][row][col0 + j] + bfu(xs[2][j]);
        const float ov = g_lds[3][row][col0 + j] + bfu(xs[3][j]);
        const float c = sigmf_(fv) * cr[j] + sigmf_(rv) * tanhf2(gv);
        cr[j] = c;
        h[j] = sigmf_(ov) * tanhf2(c);
      }
      const unsigned short b0 = packbf(h[0]), b1 = packbf(h[1]), b2 = packbf(h[2]);
      const ull_t wv = (ull_t)(unsigned short)(gs + 1)
                     | ((ull_t)b0 << 16) | ((ull_t)b1 << 32) | ((ull_t)b2 << 48);
      __hip_atomic_store(hbuf + ((size_t)((gs + 1) & 1)) * PSTR + (size_t)group * RWRD
                         + (size_t)row * WPR + slice * WPS + wloc,
                         wv, __ATOMIC_RELAXED, __HIP_MEMORY_SCOPE_AGENT);
      h_stage[row][j0 + col0]     = b0;
      h_stage[row][j0 + col0 + 1] = b1;
      h_stage[row][j0 + col0 + 2] = b2;
      unsigned short* hsp = (unsigned short*)(Hs + ((size_t)gs * B_DIM + r0 + row) * H2 + j0 + col0);
      hsp[0] = b0; hsp[1] = b1; hsp[2] = b2;
      if (chunk == 3 && s == CHUNK - 1) {
        float* hp = hT + (size_t)(r0 + row) * H_DIM + j0 + col0;
        hp[0] = h[0]; hp[1] = h[1]; hp[2] = h[2];
      }
    }
  }

  if (tid < 128) {
    float* cs = cstate + (size_t)(r0 + row) * H_DIM + j0 + col0;
    cs[0] = cr[0]; cs[1] = cr[1]; cs[2] = cr[2];
  }
}

// ---------------- hTW[b,n] = hT[b,:] @ Wh_b[:,n] ----------------
__global__ __launch_bounds__(256) void k_hTW(const float* __restrict__ hT,
                                             const float* __restrict__ Whb,
                                             float* __restrict__ hTW) {
  const int b = blockIdx.y;
  const int n = blockIdx.x * 256 + threadIdx.x;
  __shared__ float hs[768];
  for (int i = threadIdx.x; i < 768; i += 256) hs[i] = hT[b * 768 + i];
  __syncthreads();
  float acc = 0.f;
  #pragma unroll 4
  for (int k = 0; k < 768; ++k) acc += hs[k] * Whb[(size_t)k * G4 + n];
  hTW[(size_t)b * G4 + n] = acc;
}

// ---------------- backward scan over X + co-scheduled workers (3 roles) ----------------
// bx<192: elementwise backward chains over X (chunk c).
// 192<=bx<448: 256 GEMM workers producing the NEXT backward chunk's X (<=6 tiles each).
// 448<=bx: 128 out-projection workers for the chunk finished by the PREVIOUS dispatch.
// All buffer hazards are stream-ordered: each buffer written here was last read in
// the previous dispatch (X ping-pong), and out workers read Hs completed earlier.
__global__ __launch_bounds__(256) void k_bwd_scan_o(const __hip_bfloat16* __restrict__ X,
                                                    const float* __restrict__ hTW,
                                                    __hip_bfloat16* __restrict__ Hs,
                                                    float* __restrict__ c2state,
                                                    int chunk,
                                                    const __hip_bfloat16* __restrict__ EmbB,
                                                    const __hip_bfloat16* __restrict__ WiTb,
                                                    const float* __restrict__ BiasB,
                                                    __hip_bfloat16* __restrict__ Xw,
                                                    int do_gemm, int out_chunk,
                                                    const float* __restrict__ Wout,
                                                    const float* __restrict__ bout,
                                                    const int* __restrict__ tokens,
                                                    float* __restrict__ out) {
  __shared__ __align__(16) char pool[49152];
  const int bx = blockIdx.x;

  if (bx >= 448) {                     // ---- out workers (128) ----
    if (out_chunk >= 0)
      for (int ob = bx - 448; ob < 1024; ob += 128)
        out_block8(pool, out_chunk * 1024 + ob, Hs, Wout, bout, tokens, out);
    return;
  }
  if (bx >= 192) {                     // ---- GEMM workers (256) ----
    if (do_gemm)
      for (int t = bx - 192; t < NTILES; t += 256)
        gemm_tile_e(pool, t, EmbB, WiTb, BiasB, Xw);
    return;
  }

  // ---- backward scan role ----
  const int t = bx * 256 + threadIdx.x;            // 49152
  const int b = t / H_DIM;
  const int j = t % H_DIM;
  const int base = chunk * CHUNK;
  const float hw0 = hTW[(size_t)b * G4 + j];
  const float hw1 = hTW[(size_t)b * G4 + 768 + j];
  const float hw2 = hTW[(size_t)b * G4 + 1536 + j];
  const float hw3 = hTW[(size_t)b * G4 + 2304 + j];
  float c2 = c2state[t];
  for (int s = CHUNK - 1; s >= 0; --s) {
    const size_t xb = ((size_t)s * B_DIM + b) * G4 + j;
    const float r = sigmf_(__bfloat162float(X[xb]) + hw0);
    const float f = sigmf_(__bfloat162float(X[xb + 768]) + hw1);
    const float g = tanhf2(__bfloat162float(X[xb + 1536]) + hw2);
    const float o = sigmf_(__bfloat162float(X[xb + 2304]) + hw3);
    c2 = f * c2 + r * g;
    Hs[((size_t)(base + s) * B_DIM + b) * H2 + H_DIM + j] = __float2bfloat16(o * tanhf2(c2));
  }
  c2state[t] = c2;
}

// ---------------- host launcher ----------------
extern "C" void kernel_launch(void* const* d_in, const int* in_sizes, int n_in,
                              void* d_out, int out_size, void* d_ws, size_t ws_size,
                              hipStream_t stream) {
  const int*   tokens = (const int*)d_in[0];
  const float* emb    = (const float*)d_in[2];
  const float* Wi_f   = (const float*)d_in[3];
  const float* bi_f   = (const float*)d_in[4];
  const float* Wh_f   = (const float*)d_in[5];
  const float* bh_f   = (const float*)d_in[6];
  const float* Wi_b   = (const float*)d_in[7];
  const float* bi_b   = (const float*)d_in[8];
  const float* Wh_b   = (const float*)d_in[9];
  const float* bh_b   = (const float*)d_in[10];
  const float* Wout   = (const float*)d_in[11];
  const float* bout   = (const float*)d_in[12];
  float* out = (float*)d_out;
  char* ws = (char*)d_ws;

  size_t off = 0;
  auto alloc = [&](size_t bytes) { size_t o = off; off += (bytes + 255) & ~(size_t)255; return o; };
  const size_t oHs    = alloc((size_t)M_ROWS * H2 * 2);        // 100.7 MB
  const size_t oX0    = alloc((size_t)CM * G4 * 2);            // 50.3 MB
  const size_t oWhTf  = alloc((size_t)G4 * H_DIM * 2);         // 4.7 MB
  const size_t oWiTf  = alloc((size_t)G4 * E_DIM * 2);         // 3.1 MB
  const size_t oWiTb  = alloc((size_t)G4 * E_DIM * 2);         // 3.1 MB
  const size_t oBiasF = alloc((size_t)G4 * 4);
  const size_t oBiasB = alloc((size_t)G4 * 4);
  const size_t oHbuf  = alloc((size_t)2 * PSTR * 8);           // 256 KB packed h
  const size_t oCst   = alloc((size_t)B_DIM * H_DIM * 4);
  const size_t oHT    = alloc((size_t)B_DIM * H_DIM * 4);
  const size_t oHTW   = alloc((size_t)B_DIM * G4 * 4);
  const size_t oC2    = alloc((size_t)B_DIM * H_DIM * 4);
  const size_t oX1    = alloc((size_t)CM * G4 * 2);            // 50.3 MB
  const bool overlap = (off <= ws_size);                       // ~214 MB
  const size_t oEmb   = alloc((size_t)M_ROWS * E_DIM * 2);     // 33.6 MB
  const bool tierA = (off <= ws_size);                         // ~248 MB
  (void)in_sizes; (void)n_in; (void)out_size;

  __hip_bfloat16* Hs   = (__hip_bfloat16*)(ws + oHs);
  __hip_bfloat16* X0   = (__hip_bfloat16*)(ws + oX0);
  __hip_bfloat16* X1   = overlap ? (__hip_bfloat16*)(ws + oX1) : X0;
  __hip_bfloat16* Emb  = tierA ? (__hip_bfloat16*)(ws + oEmb) : (__hip_bfloat16*)nullptr;
  __hip_bfloat16* WhTf = (__hip_bfloat16*)(ws + oWhTf);
  __hip_bfloat16* WiTf = (__hip_bfloat16*)(ws + oWiTf);
  __hip_bfloat16* WiTb = (__hip_bfloat16*)(ws + oWiTb);
  float*          BiasF= (float*)(ws + oBiasF);
  float*          BiasB= (float*)(ws + oBiasB);
  ull_t*          Hbuf = (ull_t*)(ws + oHbuf);
  float*          Cst  = (float*)(ws + oCst);
  float*          HT   = (float*)(ws + oHT);
  float*          HTW  = (float*)(ws + oHTW);
  float*          C2   = (float*)(ws + oC2);

  hipMemsetAsync(ws + oHbuf, 0, (size_t)2 * PSTR * 8, stream);   // h_0 = 0, tag 0
  hipMemsetAsync(ws + oCst, 0, (size_t)B_DIM * H_DIM * 4, stream);
  hipMemsetAsync(ws + oC2, 0, (size_t)B_DIM * H_DIM * 4, stream);

  if (tierA)
    k_gather<<<8192, 256, 0, stream>>>(tokens, emb, Emb);
  k_transpose_cast<<<dim3(96, 24), 256, 0, stream>>>(Wh_f, WhTf, 768, 3072);
  k_transpose_cast<<<dim3(96, 16), 256, 0, stream>>>(Wi_f, WiTf, 512, 3072);
  k_transpose_cast<<<dim3(96, 16), 256, 0, stream>>>(Wi_b, WiTb, 512, 3072);
  k_bias<<<12, 256, 0, stream>>>(bi_f, bh_f, BiasF);
  k_bias<<<12, 256, 0, stream>>>(bi_b, bh_b, BiasB);

  auto EA = [&](int c) { return Emb + (size_t)c * CM * E_DIM; };

  if (tierA) {
    // prologue: Xf0 -> X0
    k_gemm_e<<<NTILES, 256, 0, stream>>>(Emb, WiTf, BiasF, X0);
    // forward ping-pong; fwd3 workers produce backward chunk 3's X into X0
    k_fwd_fused<<<240, 256, 0, stream>>>(X0, WhTf, Hbuf, Hs, Cst, HT, 0,
                                         EA(1), tokens, emb, WiTf, BiasF, X1);
    k_fwd_fused<<<240, 256, 0, stream>>>(X1, WhTf, Hbuf, Hs, Cst, HT, 1,
                                         EA(2), tokens, emb, WiTf, BiasF, X0);
    k_fwd_fused<<<240, 256, 0, stream>>>(X0, WhTf, Hbuf, Hs, Cst, HT, 2,
                                         EA(3), tokens, emb, WiTf, BiasF, X1);
    k_fwd_fused<<<240, 256, 0, stream>>>(X1, WhTf, Hbuf, Hs, Cst, HT, 3,
                                         EA(3), tokens, emb, WiTb, BiasB, X0);  // Xb3
    k_hTW<<<dim3(12, 64), 256, 0, stream>>>(HT, Wh_b, HTW);
    // backward: scan-over-X; workers produce next chunk's X into the freed buffer;
    // out workers trail by one dispatch.
    k_bwd_scan_o<<<576, 256, 0, stream>>>(X0, HTW, Hs, C2, 3,
                                          EA(2), WiTb, BiasB, X1, 1, -1,
                                          Wout, bout, tokens, out);
    k_bwd_scan_o<<<576, 256, 0, stream>>>(X1, HTW, Hs, C2, 2,
                                          EA(1), WiTb, BiasB, X0, 1, 3,
                                          Wout, bout, tokens, out);
    k_bwd_scan_o<<<576, 256, 0, stream>>>(X0, HTW, Hs, C2, 1,
                                          EA(0), WiTb, BiasB, X1, 1, 2,
                                          Wout, bout, tokens, out);
    k_bwd_scan_o<<<576, 256, 0, stream>>>(X1, HTW, Hs, C2, 0,
                                          nullptr, WiTb, BiasB, X0, 0, 1,
                                          Wout, bout, tokens, out);
    k_out<<<1024, 256, 0, stream>>>(Hs, Wout, bout, tokens, out);   // chunk 0
  } else if (overlap) {
    // Tier B: forward fused with gather workers; backward via materialized X
    k_gemm_g<<<NTILES, 256, 0, stream>>>(tokens, emb, WiTf, BiasF, X0);
    k_fwd_fused<<<240, 256, 0, stream>>>(X0, WhTf, Hbuf, Hs, Cst, HT, 0,
                                         nullptr, tokens + 1 * CM, emb, WiTf, BiasF, X1);
    k_fwd_fused<<<240, 256, 0, stream>>>(X1, WhTf, Hbuf, Hs, Cst, HT, 1,
                                         nullptr, tokens + 2 * CM, emb, WiTf, BiasF, X0);
    k_fwd_fused<<<240, 256, 0, stream>>>(X0, WhTf, Hbuf, Hs, Cst, HT, 2,
                                         nullptr, tokens + 3 * CM, emb, WiTf, BiasF, X1);
    k_fwd_fused<<<240, 256, 0, stream>>>(X1, WhTf, Hbuf, Hs, Cst, HT, 3,
                                         nullptr, tokens + 3 * CM, emb, WiTb, BiasB, X0);
    k_hTW<<<dim3(12, 64), 256, 0, stream>>>(HT, Wh_b, HTW);
    k_bwd_scan_o<<<192, 256, 0, stream>>>(X0, HTW, Hs, C2, 3,
                                          nullptr, WiTb, BiasB, X1, 0, -1,
                                          Wout, bout, tokens, out);
    for (int c = 2; c >= 0; --c) {
      k_gemm_g<<<NTILES, 256, 0, stream>>>(tokens + (size_t)c * CM, emb, WiTb, BiasB, X1);
      k_bwd_scan_o<<<192, 256, 0, stream>>>(X1, HTW, Hs, C2, c,
                                            nullptr, WiTb, BiasB, X0, 0, -1,
                                            Wout, bout, tokens, out);
    }
    k_out<<<4096, 256, 0, stream>>>(Hs, Wout, bout, tokens, out);
  } else {
    // sequential fallback (single X buffer, gather-fused)
    for (int c = 0; c < 4; ++c) {
      k_gemm_g<<<NTILES, 256, 0, stream>>>(tokens + (size_t)c * CM, emb, WiTf, BiasF, X0);
      k_fwd_fused<<<128, 256, 0, stream>>>(X0, WhTf, Hbuf, Hs, Cst, HT, c,
                                           nullptr, tokens, emb, WiTf, BiasF, X0);
    }
    k_hTW<<<dim3(12, 64), 256, 0, stream>>>(HT, Wh_b, HTW);
    for (int c = 3; c >= 0; --c) {
      k_gemm_g<<<NTILES, 256, 0, stream>>>(tokens + (size_t)c * CM, emb, WiTb, BiasB, X0);
      k_bwd_scan_o<<<192, 256, 0, stream>>>(X0, HTW, Hs, C2, c,
                                            nullptr, WiTb, BiasB, X0, 0, -1,
                                            Wout, bout, tokens, out);
    }
    k_out<<<4096, 256, 0, stream>>>(Hs, Wout, bout, tokens, out);
  }
}

// Round 12
// 2969.239 us; speedup vs baseline: 1.1222x; 1.1222x over previous
//
#include <hip/hip_runtime.h>
#include <hip/hip_bf16.h>
#include <stdint.h>

typedef __attribute__((ext_vector_type(8))) short bf16x8;
typedef __attribute__((ext_vector_type(4))) float f32x4;
typedef __attribute__((ext_vector_type(4))) unsigned int u32x4;
typedef unsigned long long ull_t;

#define S_LEN 512
#define B_DIM 64
#define E_DIM 512
#define H_DIM 768
#define G4    3072      // 4H (one direction's gate width)
#define H2    1536      // 2H (combined hs row)
#define M_ROWS 32768    // S*B
#define CHUNK 128       // seq steps per X-chunk
#define CM    8192      // CHUNK*B rows per chunk
#define SLW   24        // cols per slice
#define WPS   8         // published words per slice per row
#define WPR   256       // packed words per h row (256*3 = 768 cols)
#define RWRD  4096      // words per ring per parity (16 rows * 256)
#define PSTR  16384     // words per parity (4 rings)
#define KRES  640       // K columns resident in LDS (fwd scan)
#define KREG  4         // K-tail tiles in registers (fwd scan)
#define WROW  648       // padded LDS weight row, fwd (shorts)
#define NTILES 1536     // X-GEMM tiles per chunk (64 m x 24 n)

__device__ __forceinline__ float sigmf_(float x) { return 1.0f / (1.0f + __expf(-x)); }
__device__ __forceinline__ float tanhf2(float x) {
  x = fminf(fmaxf(x, -20.0f), 20.0f);
  float e = __expf(2.0f * x);
  return (e - 1.0f) / (e + 1.0f);
}
__device__ __forceinline__ float bfu(unsigned short u) { return __uint_as_float((unsigned)u << 16); }
__device__ __forceinline__ unsigned short packbf(float a) {
  __hip_bfloat16 t = __float2bfloat16(a);
  unsigned short b;
  __builtin_memcpy(&b, &t, 2);
  return b;
}

// ---------------- fused prep: gather + 3 weight transposes + 2 biases (one launch) ------
// 13592 independent blocks: [0,8192) gather; [8192,10496) Wh_f^T; [10496,12032) Wi_f^T;
// [12032,13568) Wi_b^T; [13568,13580) BiasF; [13580,13592) BiasB.
__device__ __forceinline__ void transpose_body(float (*tile)[33],
                                               const float* __restrict__ src,
                                               __hip_bfloat16* __restrict__ dst,
                                               int Rs, int Cs, int bxx, int bxy) {
  const int tx = threadIdx.x & 31, ty = threadIdx.x >> 5;
  const int c0 = bxx * 32, r0 = bxy * 32;
  #pragma unroll
  for (int i = ty; i < 32; i += 8)
    tile[i][tx] = src[(size_t)(r0 + i) * Cs + c0 + tx];
  __syncthreads();
  #pragma unroll
  for (int i = ty; i < 32; i += 8)
    dst[(size_t)(c0 + i) * Rs + r0 + tx] = __float2bfloat16(tile[tx][i]);
}

__global__ __launch_bounds__(256) void k_prep(const int* __restrict__ tokens,
                                              const float* __restrict__ emb,
                                              __hip_bfloat16* __restrict__ Emb,   // null -> skip gather
                                              const float* __restrict__ Wh_f, __hip_bfloat16* __restrict__ WhTf,
                                              const float* __restrict__ Wi_f, __hip_bfloat16* __restrict__ WiTf,
                                              const float* __restrict__ Wi_b, __hip_bfloat16* __restrict__ WiTb,
                                              const float* __restrict__ bi_f, const float* __restrict__ bh_f,
                                              float* __restrict__ BiasF,
                                              const float* __restrict__ bi_b, const float* __restrict__ bh_b,
                                              float* __restrict__ BiasB) {
  __shared__ float tile[32][33];
  int bx = blockIdx.x;
  if (bx < 8192) {                               // ---- gather role ----
    if (Emb) {
      const int t = bx * 256 + threadIdx.x;
      const int e0 = t * 8;
      const int row = e0 >> 9;
      const int k = e0 & 511;
      const int tok = tokens[row];
      const float4* p = (const float4*)(emb + (size_t)tok * E_DIM + k);
      const float4 v0 = p[0], v1 = p[1];
      __align__(16) __hip_bfloat16 tmp[8];
      tmp[0] = __float2bfloat16(v0.x); tmp[1] = __float2bfloat16(v0.y);
      tmp[2] = __float2bfloat16(v0.z); tmp[3] = __float2bfloat16(v0.w);
      tmp[4] = __float2bfloat16(v1.x); tmp[5] = __float2bfloat16(v1.y);
      tmp[6] = __float2bfloat16(v1.z); tmp[7] = __float2bfloat16(v1.w);
      *(bf16x8*)(Emb + (size_t)t * 8) = *(const bf16x8*)tmp;
    }
    return;
  }
  bx -= 8192;
  if (bx < 2304) { transpose_body(tile, Wh_f, WhTf, 768, 3072, bx % 96, bx / 96); return; }
  bx -= 2304;
  if (bx < 1536) { transpose_body(tile, Wi_f, WiTf, 512, 3072, bx % 96, bx / 96); return; }
  bx -= 1536;
  if (bx < 1536) { transpose_body(tile, Wi_b, WiTb, 512, 3072, bx % 96, bx / 96); return; }
  bx -= 1536;
  if (bx < 12) { const int n = bx * 256 + threadIdx.x; BiasF[n] = bi_f[n] + bh_f[n]; return; }
  bx -= 12;
  { const int n = bx * 256 + threadIdx.x; BiasB[n] = bi_b[n] + bh_b[n]; }
}

// ---------------- X-GEMM tile, pre-gathered bf16 A (fast path) --------
__device__ __forceinline__ void gemm_tile_e(char* pool, int tile,
                                            const __hip_bfloat16* __restrict__ A,
                                            const __hip_bfloat16* __restrict__ BT,
                                            const float* __restrict__ bias,
                                            __hip_bfloat16* __restrict__ C) {
  auto As = (__hip_bfloat16 (*)[40])pool;
  auto Bs = (__hip_bfloat16 (*)[40])(pool + 10240);
  const int tid = threadIdx.x;
  const int wave = tid >> 6, lane = tid & 63;
  const int q = lane >> 4, lr = lane & 15;
  const int wm = (wave >> 1) * 64, wn = (wave & 1) * 64;
  const int nb = tile % 24, mb = tile / 24;
  const int m0 = mb * 128, n0 = nb * 128;
  const int srow = tid >> 2, skseg = (tid & 3) * 8;

  f32x4 acc[4][4];
  #pragma unroll
  for (int i = 0; i < 4; ++i)
    #pragma unroll
    for (int j = 0; j < 4; ++j) { f32x4 z = {0.f, 0.f, 0.f, 0.f}; acc[i][j] = z; }

  for (int kt = 0; kt < 16; ++kt) {
    __syncthreads();
    const int kbase = kt * 32 + skseg;
    *(bf16x8*)&As[srow][skseg]      = *(const bf16x8*)(A + (size_t)(m0 + srow) * E_DIM + kbase);
    *(bf16x8*)&As[srow + 64][skseg] = *(const bf16x8*)(A + (size_t)(m0 + srow + 64) * E_DIM + kbase);
    *(bf16x8*)&Bs[srow][skseg]      = *(const bf16x8*)(BT + (size_t)(n0 + srow) * E_DIM + kbase);
    *(bf16x8*)&Bs[srow + 64][skseg] = *(const bf16x8*)(BT + (size_t)(n0 + srow + 64) * E_DIM + kbase);
    __syncthreads();
    bf16x8 af[4], bfr[4];
    #pragma unroll
    for (int mt = 0; mt < 4; ++mt) af[mt] = *(const bf16x8*)&As[wm + mt * 16 + lr][q * 8];
    #pragma unroll
    for (int nt = 0; nt < 4; ++nt) bfr[nt] = *(const bf16x8*)&Bs[wn + nt * 16 + lr][q * 8];
    #pragma unroll
    for (int mt = 0; mt < 4; ++mt)
      #pragma unroll
      for (int nt = 0; nt < 4; ++nt)
        acc[mt][nt] = __builtin_amdgcn_mfma_f32_16x16x32_bf16(af[mt], bfr[nt], acc[mt][nt], 0, 0, 0);
  }
  #pragma unroll
  for (int mt = 0; mt < 4; ++mt) {
    #pragma unroll
    for (int nt = 0; nt < 4; ++nt) {
      const int col = n0 + wn + nt * 16 + lr;
      const float bv = bias[col];
      #pragma unroll
      for (int i = 0; i < 4; ++i) {
        const int row = m0 + wm + mt * 16 + q * 4 + i;
        C[(size_t)row * G4 + col] = __float2bfloat16(acc[mt][nt][i] + bv);
      }
    }
  }
}

// ---------------- X-GEMM tile with fused embedding gather (fallback tiers) ----------------
__device__ __forceinline__ void gemm_tile_g(char* pool, int tile,
                                            const int* __restrict__ tokens_c,
                                            const float* __restrict__ emb,
                                            const __hip_bfloat16* __restrict__ BT,
                                            const float* __restrict__ bias,
                                            __hip_bfloat16* __restrict__ C) {
  auto As = (__hip_bfloat16 (*)[40])pool;
  auto Bs = (__hip_bfloat16 (*)[40])(pool + 10240);
  const int tid = threadIdx.x;
  const int wave = tid >> 6, lane = tid & 63;
  const int q = lane >> 4, lr = lane & 15;
  const int wm = (wave >> 1) * 64, wn = (wave & 1) * 64;
  const int nb = tile % 24, mb = tile / 24;
  const int m0 = mb * 128, n0 = nb * 128;
  const int srow = tid >> 2, skseg = (tid & 3) * 8;
  const int tok0 = tokens_c[m0 + srow];
  const int tok1 = tokens_c[m0 + srow + 64];

  f32x4 acc[4][4];
  #pragma unroll
  for (int i = 0; i < 4; ++i)
    #pragma unroll
    for (int j = 0; j < 4; ++j) { f32x4 z = {0.f, 0.f, 0.f, 0.f}; acc[i][j] = z; }

  for (int kt = 0; kt < 16; ++kt) {
    __syncthreads();
    const int kbase = kt * 32 + skseg;
    {
      const float* ap = emb + (size_t)tok0 * E_DIM + kbase;
      const float4 v0 = *(const float4*)ap, v1 = *(const float4*)(ap + 4);
      __align__(16) __hip_bfloat16 t8[8];
      t8[0] = __float2bfloat16(v0.x); t8[1] = __float2bfloat16(v0.y);
      t8[2] = __float2bfloat16(v0.z); t8[3] = __float2bfloat16(v0.w);
      t8[4] = __float2bfloat16(v1.x); t8[5] = __float2bfloat16(v1.y);
      t8[6] = __float2bfloat16(v1.z); t8[7] = __float2bfloat16(v1.w);
      *(bf16x8*)&As[srow][skseg] = *(const bf16x8*)t8;
    }
    {
      const float* ap = emb + (size_t)tok1 * E_DIM + kbase;
      const float4 v0 = *(const float4*)ap, v1 = *(const float4*)(ap + 4);
      __align__(16) __hip_bfloat16 t8[8];
      t8[0] = __float2bfloat16(v0.x); t8[1] = __float2bfloat16(v0.y);
      t8[2] = __float2bfloat16(v0.z); t8[3] = __float2bfloat16(v0.w);
      t8[4] = __float2bfloat16(v1.x); t8[5] = __float2bfloat16(v1.y);
      t8[6] = __float2bfloat16(v1.z); t8[7] = __float2bfloat16(v1.w);
      *(bf16x8*)&As[srow + 64][skseg] = *(const bf16x8*)t8;
    }
    *(bf16x8*)&Bs[srow][skseg]      = *(const bf16x8*)(BT + (size_t)(n0 + srow) * E_DIM + kbase);
    *(bf16x8*)&Bs[srow + 64][skseg] = *(const bf16x8*)(BT + (size_t)(n0 + srow + 64) * E_DIM + kbase);
    __syncthreads();
    bf16x8 af[4], bfr[4];
    #pragma unroll
    for (int mt = 0; mt < 4; ++mt) af[mt] = *(const bf16x8*)&As[wm + mt * 16 + lr][q * 8];
    #pragma unroll
    for (int nt = 0; nt < 4; ++nt) bfr[nt] = *(const bf16x8*)&Bs[wn + nt * 16 + lr][q * 8];
    #pragma unroll
    for (int mt = 0; mt < 4; ++mt)
      #pragma unroll
      for (int nt = 0; nt < 4; ++nt)
        acc[mt][nt] = __builtin_amdgcn_mfma_f32_16x16x32_bf16(af[mt], bfr[nt], acc[mt][nt], 0, 0, 0);
  }
  #pragma unroll
  for (int mt = 0; mt < 4; ++mt) {
    #pragma unroll
    for (int nt = 0; nt < 4; ++nt) {
      const int col = n0 + wn + nt * 16 + lr;
      const float bv = bias[col];
      #pragma unroll
      for (int i = 0; i < 4; ++i) {
        const int row = m0 + wm + mt * 16 + q * 4 + i;
        C[(size_t)row * G4 + col] = __float2bfloat16(acc[mt][nt][i] + bv);
      }
    }
  }
}

// ---------------- standalone X-GEMMs ----------------
__global__ __launch_bounds__(256) void k_gemm_e(const __hip_bfloat16* __restrict__ A,
                                                const __hip_bfloat16* __restrict__ BT,
                                                const float* __restrict__ bias,
                                                __hip_bfloat16* __restrict__ C) {
  __shared__ __align__(16) char pool[20480];
  gemm_tile_e(pool, blockIdx.x, A, BT, bias, C);
}
__global__ __launch_bounds__(256) void k_gemm_g(const int* __restrict__ tokens_c,
                                                const float* __restrict__ emb,
                                                const __hip_bfloat16* __restrict__ BT,
                                                const float* __restrict__ bias,
                                                __hip_bfloat16* __restrict__ C) {
  __shared__ __align__(16) char pool[20480];
  gemm_tile_g(pool, blockIdx.x, tokens_c, emb, BT, bias, C);
}

// ---------------- output projection ----------------
__global__ __launch_bounds__(256) void k_out(const __hip_bfloat16* __restrict__ Hs,
                                             const float* __restrict__ Wout,
                                             const float* __restrict__ bout,
                                             const int* __restrict__ tokens,
                                             float* __restrict__ out) {
  __shared__ float rowbuf[8][1536];
  const int r0 = blockIdx.x * 8;
  const int tid = threadIdx.x;
  for (int idx = tid; idx < 8 * 1536; idx += 256) {
    const int rr = idx / 1536, k = idx % 1536;
    rowbuf[rr][k] = __bfloat162float(Hs[(size_t)(r0 + rr) * H2 + k]);
  }
  __syncthreads();
  const int l = tid & 31, rr = tid >> 5;
  float acc = bout[l];
  #pragma unroll 8
  for (int k = 0; k < 1536; ++k) acc += rowbuf[rr][k] * Wout[k * 32 + l];
  const int row = r0 + rr;
  if (l == 0 && tokens[row] == 1) acc += 10000.0f;
  out[(size_t)row * 32 + l] = acc;
}

// ---------------- forward scan (+ co-scheduled X-GEMM workers) ----------------
// Blocks 0..127: verified tag-in-data systolic scan. Blocks 128+: persistent GEMM
// workers producing one X (next fwd chunk's, or for fwd3: backward chunk 3's).
// Worker fusion is valid here because the scan is LATENCY-bound with idle bandwidth
// (R5/R11 measured: workers add <1.5% to scan time). Do NOT co-schedule two
// bandwidth-bound roles (R11 lesson: scan-over-X + gemm co-resident = +90us each).
__global__ __launch_bounds__(256, 1) void k_fwd_fused(const __hip_bfloat16* __restrict__ X,
                                                      const __hip_bfloat16* __restrict__ WhTf,
                                                      ull_t* __restrict__ hbuf,
                                                      __hip_bfloat16* __restrict__ Hs,
                                                      float* __restrict__ cstate,
                                                      float* __restrict__ hT,
                                                      int chunk,
                                                      const __hip_bfloat16* __restrict__ EmbA,
                                                      const int* __restrict__ tokens_nx,
                                                      const float* __restrict__ emb,
                                                      const __hip_bfloat16* __restrict__ WiT_nx,
                                                      const float* __restrict__ Bias_nx,
                                                      __hip_bfloat16* __restrict__ Xw) {
  __shared__ __align__(16) char pool[155904];
  const int bx = blockIdx.x;

  if (bx >= 128) {                       // ---- GEMM worker role ----
    const int nw = gridDim.x - 128;
    if (EmbA) {
      for (int t = bx - 128; t < NTILES; t += nw)
        gemm_tile_e(pool, t, EmbA, WiT_nx, Bias_nx, Xw);
    } else {
      for (int t = bx - 128; t < NTILES; t += nw)
        gemm_tile_g(pool, t, tokens_nx, emb, WiT_nx, Bias_nx, Xw);
    }
    return;
  }

  // ---- scan role: identical to the verified R4 kernel ----
  unsigned short* wlds = (unsigned short*)pool;                       // 124,416 B
  auto h_stage = (unsigned short (*)[776])(pool + 124416);            //  24,832 B
  auto g_lds   = (float (*)[16][26])(pool + 149248);                  //   6,656 B

  const int group = bx >> 5;
  const int slice = bx & 31;
  const int r0 = group * 16;
  const int j0 = slice * SLW;
  const int tid = threadIdx.x;
  const int w = tid >> 6;
  const int lane = tid & 63;
  const int q = lane >> 4, lr = lane & 15;
  const int base = chunk * CHUNK;

  const int prow = tid >> 4;
  const int pw   = tid & 15;

  const int row  = tid >> 3;
  const int wloc = tid & 7;
  const int col0 = 3 * wloc;

  for (int c = tid; c < 96 * (KRES / 8); c += 256) {
    const int r = c / (KRES / 8), k8 = c % (KRES / 8);
    const int gate = r / SLW, n = r % SLW;
    const float4 v = *(const float4*)(WhTf + (size_t)(gate * H_DIM + j0 + n) * H_DIM + k8 * 8);
    *(float4*)(wlds + (size_t)r * WROW + k8 * 8) = v;
  }

  const int wn0 = lr;
  const int wn1 = 16 + (lr & 7);
  bf16x8 wr0[KREG], wr1[KREG];
  #pragma unroll
  for (int kk = 0; kk < KREG; ++kk) {
    const int ko = KRES + kk * 32 + q * 8;
    wr0[kk] = *(const bf16x8*)(WhTf + (size_t)(w * H_DIM + j0 + wn0) * H_DIM + ko);
    wr1[kk] = *(const bf16x8*)(WhTf + (size_t)(w * H_DIM + j0 + wn1) * H_DIM + ko);
  }

  float cr[3] = {0.f, 0.f, 0.f};
  if (tid < 128) {
    const float* cs = cstate + (size_t)(r0 + row) * H_DIM + j0 + col0;
    cr[0] = cs[0]; cr[1] = cs[1]; cr[2] = cs[2];
  }

  const unsigned skipbit = ((pw >> 2) == (slice & 3)) ? (1u << (slice >> 2)) : 0u;

  __syncthreads();

  for (int s = 0; s < CHUNK; ++s) {
    const int gs = base + s;

    unsigned short xs[4][3];
    if (tid < 128) {
      const unsigned short* xp = (const unsigned short*)(X + ((size_t)s * B_DIM + r0 + row) * G4 + j0 + col0);
      #pragma unroll
      for (int g = 0; g < 4; ++g)
        #pragma unroll
        for (int j = 0; j < 3; ++j) xs[g][j] = xp[g * H_DIM + j];
    }

    const ull_t* hc = hbuf + ((size_t)(gs & 1)) * PSTR + (size_t)group * RWRD
                    + (size_t)prow * WPR + 2 * pw;
    u32x4 d0 = {0,0,0,0}, d1 = {0,0,0,0}, d2 = {0,0,0,0}, d3 = {0,0,0,0};
    u32x4 d4 = {0,0,0,0}, d5 = {0,0,0,0}, d6 = {0,0,0,0}, d7 = {0,0,0,0};
    const unsigned pollmask = (s == 0) ? 0xFFu : (0xFFu ^ skipbit);
    {
      const unsigned e16 = (unsigned)(unsigned short)gs;
      unsigned need = pollmask;
      long guard = 0;
      for (;;) {
#define POLL_LD(i, dv) \
        if (need & (1u << (i))) \
          asm volatile("global_load_dwordx4 %0, %1, off sc0 sc1" \
                       : "=v"(dv) : "v"(hc + 32 * (i)) : "memory");
        POLL_LD(0, d0) POLL_LD(1, d1) POLL_LD(2, d2) POLL_LD(3, d3)
        POLL_LD(4, d4) POLL_LD(5, d5) POLL_LD(6, d6) POLL_LD(7, d7)
#undef POLL_LD
        asm volatile("s_waitcnt vmcnt(0)"
                     : "+v"(d0), "+v"(d1), "+v"(d2), "+v"(d3),
                       "+v"(d4), "+v"(d5), "+v"(d6), "+v"(d7)
                     :: "memory");
        unsigned nn = 0;
#define POLL_CK(i, dv) \
        if ((need & (1u << (i))) && \
            ((((dv).x & 0xFFFFu) != e16) || (((dv).z & 0xFFFFu) != e16))) nn |= 1u << (i);
        POLL_CK(0, d0) POLL_CK(1, d1) POLL_CK(2, d2) POLL_CK(3, d3)
        POLL_CK(4, d4) POLL_CK(5, d5) POLL_CK(6, d6) POLL_CK(7, d7)
#undef POLL_CK
        need = nn;
        if (!need) break;
        if (++guard > (1L << 20)) break;
        __builtin_amdgcn_s_sleep(1);
      }
    }
    {
#define STAGE_PAIR(i, dv) \
      if (pollmask & (1u << (i))) { \
        unsigned* hp = (unsigned*)&h_stage[prow][6 * pw + 96 * (i)]; \
        hp[0] = ((dv).x >> 16) | ((dv).y << 16); \
        hp[1] = ((dv).y >> 16) | ((dv).z & 0xFFFF0000u); \
        hp[2] = (dv).w; \
      }
      STAGE_PAIR(0, d0) STAGE_PAIR(1, d1) STAGE_PAIR(2, d2) STAGE_PAIR(3, d3)
      STAGE_PAIR(4, d4) STAGE_PAIR(5, d5) STAGE_PAIR(6, d6) STAGE_PAIR(7, d7)
#undef STAGE_PAIR
    }
    __syncthreads();   // B1: h staged

    f32x4 acc0 = {0.f, 0.f, 0.f, 0.f};
    f32x4 acc1 = {0.f, 0.f, 0.f, 0.f};
    {
      const unsigned short* wb = wlds + (size_t)w * SLW * WROW;
      #pragma unroll
      for (int kt = 0; kt < KRES / 32; ++kt) {
        const int ko = kt * 32 + q * 8;
        const bf16x8 a  = *(const bf16x8*)&h_stage[lr][ko];
        const bf16x8 b0 = *(const bf16x8*)(wb + (size_t)wn0 * WROW + ko);
        const bf16x8 b1 = *(const bf16x8*)(wb + (size_t)wn1 * WROW + ko);
        acc0 = __builtin_amdgcn_mfma_f32_16x16x32_bf16(a, b0, acc0, 0, 0, 0);
        acc1 = __builtin_amdgcn_mfma_f32_16x16x32_bf16(a, b1, acc1, 0, 0, 0);
      }
      #pragma unroll
      for (int kk = 0; kk < KREG; ++kk) {
        const bf16x8 a = *(const bf16x8*)&h_stage[lr][KRES + kk * 32 + q * 8];
        acc0 = __builtin_amdgcn_mfma_f32_16x16x32_bf16(a, wr0[kk], acc0, 0, 0, 0);
        acc1 = __builtin_amdgcn_mfma_f32_16x16x32_bf16(a, wr1[kk], acc1, 0, 0, 0);
      }
    }
    #pragma unroll
    for (int i = 0; i < 4; ++i) g_lds[w][q * 4 + i][lr] = acc0[i];
    if (lr < 8) {
      #pragma unroll
      for (int i = 0; i < 4; ++i) g_lds[w][q * 4 + i][16 + lr] = acc1[i];
    }
    __syncthreads();   // B2: gates ready

    if (tid < 128) {
      float h[3];
      #pragma unroll
      for (int j = 0; j < 3; ++j) {
        const float rv = g_lds[0][row][col0 + j] + bfu(xs[0][j]);
        const float fv = g_lds[1][row][col0 + j] + bfu(xs[1][j]);
        const float gv = g_lds[2][row][col0 + j] + bfu(xs[2][j]);
        const float ov = g_lds[3][row][col0 + j] + bfu(xs[3][j]);
        const float c = sigmf_(fv) * cr[j] + sigmf_(rv) * tanhf2(gv);
        cr[j] = c;
        h[j] = sigmf_(ov) * tanhf2(c);
      }
      const unsigned short b0 = packbf(h[0]), b1 = packbf(h[1]), b2 = packbf(h[2]);
      const ull_t wv = (ull_t)(unsigned short)(gs + 1)
                     | ((ull_t)b0 << 16) | ((ull_t)b1 << 32) | ((ull_t)b2 << 48);
      __hip_atomic_store(hbuf + ((size_t)((gs + 1) & 1)) * PSTR + (size_t)group * RWRD
                         + (size_t)row * WPR + slice * WPS + wloc,
                         wv, __ATOMIC_RELAXED, __HIP_MEMORY_SCOPE_AGENT);
      h_stage[row][j0 + col0]     = b0;
      h_stage[row][j0 + col0 + 1] = b1;
      h_stage[row][j0 + col0 + 2] = b2;
      unsigned short* hsp = (unsigned short*)(Hs + ((size_t)gs * B_DIM + r0 + row) * H2 + j0 + col0);
      hsp[0] = b0; hsp[1] = b1; hsp[2] = b2;
      if (chunk == 3 && s == CHUNK - 1) {
        float* hp = hT + (size_t)(r0 + row) * H_DIM + j0 + col0;
        hp[0] = h[0]; hp[1] = h[1]; hp[2] = h[2];
      }
    }
  }

  if (tid < 128) {
    float* cs = cstate + (size_t)(r0 + row) * H_DIM + j0 + col0;
    cs[0] = cr[0]; cs[1] = cr[1]; cs[2] = cr[2];
  }
}

// ---------------- hTW[b,n] = hT[b,:] @ Wh_b[:,n] ----------------
__global__ __launch_bounds__(256) void k_hTW(const float* __restrict__ hT,
                                             const float* __restrict__ Whb,
                                             float* __restrict__ hTW) {
  const int b = blockIdx.y;
  const int n = blockIdx.x * 256 + threadIdx.x;
  __shared__ float hs[768];
  for (int i = threadIdx.x; i < 768; i += 256) hs[i] = hT[b * 768 + i];
  __syncthreads();
  float acc = 0.f;
  #pragma unroll 4
  for (int k = 0; k < 768; ++k) acc += hs[k] * Whb[(size_t)k * G4 + n];
  hTW[(size_t)b * G4 + n] = acc;
}

// ---------------- backward scan over precomputed X (standalone; bandwidth-bound) -------
__global__ __launch_bounds__(256) void k_bwd_scan(const __hip_bfloat16* __restrict__ X,
                                                  const float* __restrict__ hTW,
                                                  __hip_bfloat16* __restrict__ Hs,
                                                  float* __restrict__ c2state,
                                                  int chunk) {
  const int t = blockIdx.x * 256 + threadIdx.x;    // 49152
  const int b = t / H_DIM;
  const int j = t % H_DIM;
  const int base = chunk * CHUNK;
  const float hw0 = hTW[(size_t)b * G4 + j];
  const float hw1 = hTW[(size_t)b * G4 + 768 + j];
  const float hw2 = hTW[(size_t)b * G4 + 1536 + j];
  const float hw3 = hTW[(size_t)b * G4 + 2304 + j];
  float c2 = c2state[t];
  for (int s = CHUNK - 1; s >= 0; --s) {
    const size_t xb = ((size_t)s * B_DIM + b) * G4 + j;
    const float r = sigmf_(__bfloat162float(X[xb]) + hw0);
    const float f = sigmf_(__bfloat162float(X[xb + 768]) + hw1);
    const float g = tanhf2(__bfloat162float(X[xb + 1536]) + hw2);
    const float o = sigmf_(__bfloat162float(X[xb + 2304]) + hw3);
    c2 = f * c2 + r * g;
    Hs[((size_t)(base + s) * B_DIM + b) * H2 + H_DIM + j] = __float2bfloat16(o * tanhf2(c2));
  }
  c2state[t] = c2;
}

// ---------------- host launcher ----------------
extern "C" void kernel_launch(void* const* d_in, const int* in_sizes, int n_in,
                              void* d_out, int out_size, void* d_ws, size_t ws_size,
                              hipStream_t stream) {
  const int*   tokens = (const int*)d_in[0];
  const float* emb    = (const float*)d_in[2];
  const float* Wi_f   = (const float*)d_in[3];
  const float* bi_f   = (const float*)d_in[4];
  const float* Wh_f   = (const float*)d_in[5];
  const float* bh_f   = (const float*)d_in[6];
  const float* Wi_b   = (const float*)d_in[7];
  const float* bi_b   = (const float*)d_in[8];
  const float* Wh_b   = (const float*)d_in[9];
  const float* bh_b   = (const float*)d_in[10];
  const float* Wout   = (const float*)d_in[11];
  const float* bout   = (const float*)d_in[12];
  float* out = (float*)d_out;
  char* ws = (char*)d_ws;

  size_t off = 0;
  auto alloc = [&](size_t bytes) { size_t o = off; off += (bytes + 255) & ~(size_t)255; return o; };
  const size_t oHs    = alloc((size_t)M_ROWS * H2 * 2);        // 100.7 MB
  const size_t oX0    = alloc((size_t)CM * G4 * 2);            // 50.3 MB
  const size_t oWhTf  = alloc((size_t)G4 * H_DIM * 2);         // 4.7 MB
  const size_t oWiTf  = alloc((size_t)G4 * E_DIM * 2);         // 3.1 MB
  const size_t oWiTb  = alloc((size_t)G4 * E_DIM * 2);         // 3.1 MB
  const size_t oBiasF = alloc((size_t)G4 * 4);
  const size_t oBiasB = alloc((size_t)G4 * 4);
  const size_t oHbuf  = alloc((size_t)2 * PSTR * 8);           // 256 KB packed h
  const size_t oCst   = alloc((size_t)B_DIM * H_DIM * 4);
  const size_t oHT    = alloc((size_t)B_DIM * H_DIM * 4);
  const size_t oHTW   = alloc((size_t)B_DIM * G4 * 4);
  const size_t oC2    = alloc((size_t)B_DIM * H_DIM * 4);
  const size_t oX1    = alloc((size_t)CM * G4 * 2);            // 50.3 MB
  const bool overlap = (off <= ws_size);                       // ~214 MB
  const size_t oEmb   = alloc((size_t)M_ROWS * E_DIM * 2);     // 33.6 MB
  const bool tierA = (off <= ws_size);                         // ~248 MB
  (void)in_sizes; (void)n_in; (void)out_size;

  __hip_bfloat16* Hs   = (__hip_bfloat16*)(ws + oHs);
  __hip_bfloat16* X0   = (__hip_bfloat16*)(ws + oX0);
  __hip_bfloat16* X1   = overlap ? (__hip_bfloat16*)(ws + oX1) : X0;
  __hip_bfloat16* Emb  = tierA ? (__hip_bfloat16*)(ws + oEmb) : (__hip_bfloat16*)nullptr;
  __hip_bfloat16* WhTf = (__hip_bfloat16*)(ws + oWhTf);
  __hip_bfloat16* WiTf = (__hip_bfloat16*)(ws + oWiTf);
  __hip_bfloat16* WiTb = (__hip_bfloat16*)(ws + oWiTb);
  float*          BiasF= (float*)(ws + oBiasF);
  float*          BiasB= (float*)(ws + oBiasB);
  ull_t*          Hbuf = (ull_t*)(ws + oHbuf);
  float*          Cst  = (float*)(ws + oCst);
  float*          HT   = (float*)(ws + oHT);
  float*          HTW  = (float*)(ws + oHTW);
  float*          C2   = (float*)(ws + oC2);

  hipMemsetAsync(ws + oHbuf, 0, (size_t)2 * PSTR * 8, stream);   // h_0 = 0, tag 0
  hipMemsetAsync(ws + oCst, 0, (size_t)B_DIM * H_DIM * 4, stream);
  hipMemsetAsync(ws + oC2, 0, (size_t)B_DIM * H_DIM * 4, stream);

  // fused prep: gather + weight transposes + biases (one launch)
  k_prep<<<13592, 256, 0, stream>>>(tokens, emb, Emb,
                                    Wh_f, WhTf, Wi_f, WiTf, Wi_b, WiTb,
                                    bi_f, bh_f, BiasF, bi_b, bh_b, BiasB);

  auto EA = [&](int c) { return Emb + (size_t)c * CM * E_DIM; };

  if (tierA) {
    // prologue: Xf0 -> X0
    k_gemm_e<<<NTILES, 256, 0, stream>>>(Emb, WiTf, BiasF, X0);
    // forward ping-pong; fwd3 workers produce backward chunk 3's X into X0
    k_fwd_fused<<<240, 256, 0, stream>>>(X0, WhTf, Hbuf, Hs, Cst, HT, 0,
                                         EA(1), tokens, emb, WiTf, BiasF, X1);
    k_fwd_fused<<<240, 256, 0, stream>>>(X1, WhTf, Hbuf, Hs, Cst, HT, 1,
                                         EA(2), tokens, emb, WiTf, BiasF, X0);
    k_fwd_fused<<<240, 256, 0, stream>>>(X0, WhTf, Hbuf, Hs, Cst, HT, 2,
                                         EA(3), tokens, emb, WiTf, BiasF, X1);
    k_fwd_fused<<<240, 256, 0, stream>>>(X1, WhTf, Hbuf, Hs, Cst, HT, 3,
                                         EA(3), tokens, emb, WiTb, BiasB, X0);  // Xb3
    k_hTW<<<dim3(12, 64), 256, 0, stream>>>(HT, Wh_b, HTW);
    // backward: SEQUENTIAL gemm + scan (both bandwidth-bound; do not co-schedule)
    k_bwd_scan<<<192, 256, 0, stream>>>(X0, HTW, Hs, C2, 3);
    k_gemm_e<<<NTILES, 256, 0, stream>>>(EA(2), WiTb, BiasB, X1);
    k_bwd_scan<<<192, 256, 0, stream>>>(X1, HTW, Hs, C2, 2);
    k_gemm_e<<<NTILES, 256, 0, stream>>>(EA(1), WiTb, BiasB, X0);
    k_bwd_scan<<<192, 256, 0, stream>>>(X0, HTW, Hs, C2, 1);
    k_gemm_e<<<NTILES, 256, 0, stream>>>(EA(0), WiTb, BiasB, X1);
    k_bwd_scan<<<192, 256, 0, stream>>>(X1, HTW, Hs, C2, 0);
    k_out<<<4096, 256, 0, stream>>>(Hs, Wout, bout, tokens, out);
  } else if (overlap) {
    // Tier B: forward fused with gather workers; backward sequential gather-fused
    k_gemm_g<<<NTILES, 256, 0, stream>>>(tokens, emb, WiTf, BiasF, X0);
    k_fwd_fused<<<240, 256, 0, stream>>>(X0, WhTf, Hbuf, Hs, Cst, HT, 0,
                                         nullptr, tokens + 1 * CM, emb, WiTf, BiasF, X1);
    k_fwd_fused<<<240, 256, 0, stream>>>(X1, WhTf, Hbuf, Hs, Cst, HT, 1,
                                         nullptr, tokens + 2 * CM, emb, WiTf, BiasF, X0);
    k_fwd_fused<<<240, 256, 0, stream>>>(X0, WhTf, Hbuf, Hs, Cst, HT, 2,
                                         nullptr, tokens + 3 * CM, emb, WiTf, BiasF, X1);
    k_fwd_fused<<<240, 256, 0, stream>>>(X1, WhTf, Hbuf, Hs, Cst, HT, 3,
                                         nullptr, tokens + 3 * CM, emb, WiTb, BiasB, X0);
    k_hTW<<<dim3(12, 64), 256, 0, stream>>>(HT, Wh_b, HTW);
    k_bwd_scan<<<192, 256, 0, stream>>>(X0, HTW, Hs, C2, 3);
    for (int c = 2; c >= 0; --c) {
      k_gemm_g<<<NTILES, 256, 0, stream>>>(tokens + (size_t)c * CM, emb, WiTb, BiasB, X1);
      k_bwd_scan<<<192, 256, 0, stream>>>(X1, HTW, Hs, C2, c);
    }
    k_out<<<4096, 256, 0, stream>>>(Hs, Wout, bout, tokens, out);
  } else {
    // sequential fallback (single X buffer, gather-fused)
    for (int c = 0; c < 4; ++c) {
      k_gemm_g<<<NTILES, 256, 0, stream>>>(tokens + (size_t)c * CM, emb, WiTf, BiasF, X0);
      k_fwd_fused<<<128, 256, 0, stream>>>(X0, WhTf, Hbuf, Hs, Cst, HT, c,
                                           nullptr, tokens, emb, WiTf, BiasF, X0);
    }
    k_hTW<<<dim3(12, 64), 256, 0, stream>>>(HT, Wh_b, HTW);
    for (int c = 3; c >= 0; --c) {
      k_gemm_g<<<NTILES, 256, 0, stream>>>(tokens + (size_t)c * CM, emb, WiTb, BiasB, X0);
      k_bwd_scan<<<192, 256, 0, stream>>>(X0, HTW, Hs, C2, c);
    }
    k_out<<<4096, 256, 0, stream>>>(Hs, Wout, bout, tokens, out);
  }
}